// Round 3
// baseline (339.640 us; speedup 1.0000x reference)
//
#include <hip/hip_runtime.h>

typedef int v4i  __attribute__((ext_vector_type(4)));
typedef int v16i __attribute__((ext_vector_type(16)));

__device__ __forceinline__ int pack4i(int a, int b, int c, int d) {
  return (a & 255) | ((b & 255) << 8) | ((c & 255) << 16) | ((d & 255) << 24);
}
// SWAR per-byte add (mod-256 per lane-byte)
__device__ __forceinline__ int badd4(int a, int b) {
  return ((a & 0x7f7f7f7f) + (b & 0x7f7f7f7f)) ^ ((a ^ b) & 0x80808080);
}

// ---------------------------------------------------------------------------
// Pack (W + E) -> int8, transposed Bt[n][k] (row stride K bytes).
// Tile: 64 n x 256 k per block, 256 threads. Zero-pads n >= N rows.
// LDS: 256 k-rows x 68 B stride = 17408 B.
// ---------------------------------------------------------------------------
__device__ void pack_tile(const int* __restrict__ W, const int* __restrict__ E,
                          char* __restrict__ Bt, int K, int N,
                          int nx, int ky, char* lin) {
  const int t = threadIdx.x;
  const int n0 = nx * 64, k0 = ky * 256;
  {
    const int c  = t & 15;          // column group: 4 ints = 16 B
    const int kq = t >> 4;          // 0..15
    const int ng = n0 + c * 4;
    #pragma unroll 4
    for (int s = 0; s < 16; ++s) {
      const int k = s * 16 + kq;
      const long grow = (long)(k0 + k) * N;
      int a0, a1, a2, a3;
      if (ng + 3 < N) {
        int4 wv = *(const int4*)(W + grow + ng);
        int4 ev = *(const int4*)(E + grow + ng);
        a0 = wv.x + ev.x; a1 = wv.y + ev.y; a2 = wv.z + ev.z; a3 = wv.w + ev.w;
      } else {
        a0 = (ng + 0 < N) ? W[grow + ng + 0] + E[grow + ng + 0] : 0;
        a1 = (ng + 1 < N) ? W[grow + ng + 1] + E[grow + ng + 1] : 0;
        a2 = (ng + 2 < N) ? W[grow + ng + 2] + E[grow + ng + 2] : 0;
        a3 = (ng + 3 < N) ? W[grow + ng + 3] + E[grow + ng + 3] : 0;
      }
      *(int*)(lin + k * 68 + c * 4) = pack4i(a0, a1, a2, a3);
    }
  }
  __syncthreads();
  {
    const int n = t & 63, kq = t >> 6;
    char* dst = Bt + (long)(n0 + n) * K + k0 + (kq << 6);
    int outv[16];
    #pragma unroll
    for (int g = 0; g < 16; ++g) {
      const int k = (kq << 6) + (g << 2);
      outv[g] = pack4i(lin[(k + 0) * 68 + n], lin[(k + 1) * 68 + n],
                       lin[(k + 2) * 68 + n], lin[(k + 3) * 68 + n]);
    }
    #pragma unroll
    for (int g = 0; g < 4; ++g)
      *(int4*)(dst + (g << 4)) =
          make_int4(outv[g * 4], outv[g * 4 + 1], outv[g * 4 + 2], outv[g * 4 + 3]);
  }
}

// ---------------------------------------------------------------------------
// Weights + biases. 265 blocks. (R2 showed this is small — not in top-5.)
// ---------------------------------------------------------------------------
__global__ __launch_bounds__(256) void pack_weights_kernel(
    const int* W1, const int* E1, char* Bt1,
    const int* W2, const int* E2, char* Bt2,
    const int* W3, const int* E3, char* Bt3,
    const int* b1, const int* eb1, int* bs1,
    const int* b2, const int* eb2, int* bs2,
    const int* b3, const int* eb3, int* bs3) {
  __shared__ __align__(16) char smem[17408];
  const int bid = blockIdx.x;
  if (bid < 192) {
    pack_tile(W1, E1, Bt1, 3072, 1024, bid % 16, bid / 16, smem);
  } else if (bid < 256) {
    const int l = bid - 192;
    pack_tile(W2, E2, Bt2, 1024, 1024, l % 16, l / 16, smem);
  } else if (bid < 264) {
    const int l = bid - 256;
    pack_tile(W3, E3, Bt3, 1024, 100, l & 1, l >> 1, smem);
  } else {
    const int t = threadIdx.x;
    for (int i = t; i < 1024; i += 256) {
      bs1[i] = b1[i] + eb1[i];
      bs2[i] = b2[i] + eb2[i];
    }
    for (int i = t; i < 128; i += 256)
      bs3[i] = (i < 100) ? (b3[i] + eb3[i]) : 0;
  }
}

// ---------------------------------------------------------------------------
// Layer 1 GEMM, FUSED input packing (R3). R2 proved the standalone X/H
// narrowing copy is rate-capped at ~2.7 TB/s logical no matter how it's
// written (DMA-LDS == reg-dword == reg-int4, all 62-78 us) — so it is
// removed entirely. This kernel reads X as int32 in the A-staging path and
// packs to int8 in registers before the LDS write; the epilogue reads H as
// int32 and truncate-packs before the SWAR add. 8 blocks sharing an A-panel
// are congruent mod 8 -> same XCD L2 serves the 8x int32 re-reads.
// 64x128 tile, BK=64, 256 thr (4 waves, each 64x32), 2-stage LDS dbuf.
// ---------------------------------------------------------------------------
__global__ __launch_bounds__(256, 4) void gemm1_kernel(
    const int* __restrict__ X, const char* __restrict__ Btg,
    const int* __restrict__ bsum, const int* __restrict__ H,
    char* __restrict__ A8out) {
  const int K = 3072;
  // stage: As [64][80] (5120) + Bs [128][80] (10240) = 15360; x2 = 30720
  __shared__ __align__(16) char smem[30720];

  const int t = threadIdx.x;
  const int bid = blockIdx.x;
  const int mt = bid & 127, nt = bid >> 7;
  const long m0 = (long)mt << 6;
  const int n0 = nt << 7;

  const int lane = t & 63, w = t >> 6;
  const int lc = lane & 31, hg = lane >> 5;

  v16i acc[2] = {};

  // A staging: 64 rows x 4 thr; each thr: 16 ints (64 B) -> 16 B packed
  const int am = t >> 2, ah = t & 3;
  const int* Xrow = X + (m0 + am) * (long)K + ah * 16;
  const int aoff = am * 80 + ah * 16;
  // B staging: 128 rows x 2 thr x 32 B (already int8 in Bt1)
  const int bm = t >> 1, bh = t & 1;
  const char* Brow = Btg + (long)(n0 + bm) * K + bh * 32;
  const int boff = bm * 80 + bh * 32;

  const int abo = lc * 80 + hg * 16;
  const int bbo = (w * 32 + lc) * 80 + hg * 16;

  int4 a0r, a1r, a2r, a3r, br0, br1;
  auto LOAD = [&](int kb) {            // kb = k element offset
    const int* p = Xrow + kb;
    a0r = *(const int4*)(p);
    a1r = *(const int4*)(p + 4);
    a2r = *(const int4*)(p + 8);
    a3r = *(const int4*)(p + 12);
    br0 = *(const int4*)(Brow + kb);
    br1 = *(const int4*)(Brow + kb + 16);
  };
  auto STORE = [&](int stage) {
    char* base = smem + stage * 15360;
    *(int4*)(base + aoff) = make_int4(
        pack4i(a0r.x, a0r.y, a0r.z, a0r.w),
        pack4i(a1r.x, a1r.y, a1r.z, a1r.w),
        pack4i(a2r.x, a2r.y, a2r.z, a2r.w),
        pack4i(a3r.x, a3r.y, a3r.z, a3r.w));
    *(int4*)(base + 5120 + boff)      = br0;
    *(int4*)(base + 5120 + boff + 16) = br1;
  };

  const int kiters = K >> 6;           // 48
  LOAD(0);
  STORE(0);
  __syncthreads();

  for (int kt = 0; kt < kiters; ++kt) {
    if (kt + 1 < kiters) LOAD((kt + 1) << 6);   // in flight during MFMA
    const char* base = smem + (kt & 1) * 15360;
    const char* Ab = base + abo;
    const char* Bb = base + 5120 + bbo;
    #pragma unroll
    for (int ks = 0; ks < 2; ++ks) {
      v4i a0 = *(const v4i*)(Ab + ks * 32);
      v4i a1 = *(const v4i*)(Ab + 32 * 80 + ks * 32);
      v4i b  = *(const v4i*)(Bb + ks * 32);
      acc[0] = __builtin_amdgcn_mfma_i32_32x32x32_i8(a0, b, acc[0], 0, 0, 0);
      acc[1] = __builtin_amdgcn_mfma_i32_32x32x32_i8(a1, b, acc[1], 0, 0, 0);
    }
    if (kt + 1 < kiters) {
      STORE((kt + 1) & 1);   // buffer fenced by previous barrier
      __syncthreads();
    }
  }

  // Epilogue. C/D layout: col = lane&31, row = (reg&3) + 8*(reg>>2) + 4*hg.
  const int gcl = w * 32 + lc;
  const int bs = bsum[n0 + gcl];
  __syncthreads();   // smem reused as 64x144 transpose buffer
  #pragma unroll
  for (int tm = 0; tm < 2; ++tm) {
    #pragma unroll
    for (int r = 0; r < 16; ++r) {
      const int row = tm * 32 + (hg << 2) + (r & 3) + ((r >> 2) << 3);
      smem[row * 144 + gcl] = (char)(acc[tm][r] + bs);
    }
  }
  __syncthreads();
  // readout: thread -> row t>>2, 32 bytes at (t&3)*32 ; add H (int32, fused
  // truncation) via SWAR
  const char* src = smem + (t >> 2) * 144 + (t & 3) * 32;
  const long gm = m0 + (t >> 2);
  const long gco = gm * 1024 + n0 + (t & 3) * 32;
  const int* hp = H + gco;             // one int32 per output byte
  int4 s0 = *(const int4*)(src);
  int4 s1 = *(const int4*)(src + 16);
  int4 h0 = *(const int4*)(hp);
  int4 h1 = *(const int4*)(hp + 4);
  int4 h2 = *(const int4*)(hp + 8);
  int4 h3 = *(const int4*)(hp + 12);
  int4 h4 = *(const int4*)(hp + 16);
  int4 h5 = *(const int4*)(hp + 20);
  int4 h6 = *(const int4*)(hp + 24);
  int4 h7 = *(const int4*)(hp + 28);
  s0 = make_int4(badd4(s0.x, pack4i(h0.x, h0.y, h0.z, h0.w)),
                 badd4(s0.y, pack4i(h1.x, h1.y, h1.z, h1.w)),
                 badd4(s0.z, pack4i(h2.x, h2.y, h2.z, h2.w)),
                 badd4(s0.w, pack4i(h3.x, h3.y, h3.z, h3.w)));
  s1 = make_int4(badd4(s1.x, pack4i(h4.x, h4.y, h4.z, h4.w)),
                 badd4(s1.y, pack4i(h5.x, h5.y, h5.z, h5.w)),
                 badd4(s1.z, pack4i(h6.x, h6.y, h6.z, h6.w)),
                 badd4(s1.w, pack4i(h7.x, h7.y, h7.z, h7.w)));
  *(int4*)(A8out + gco)      = s0;
  *(int4*)(A8out + gco + 16) = s1;
}

// ---------------------------------------------------------------------------
// Layer 2 GEMM: 64x128 tile, BK=64, int8 A from ws. (Verified R5/R8 shape.)
// Iout = trunc8(acc+bs) as int32, direct.
// ---------------------------------------------------------------------------
__global__ __launch_bounds__(256, 4) void gemm2_kernel(
    const char* __restrict__ A, const char* __restrict__ Btg,
    const int* __restrict__ bsum, int* __restrict__ Iout) {
  const int K = 1024;
  __shared__ __align__(16) char smem[30720];

  const int t = threadIdx.x;
  const int bid = blockIdx.x;
  const int mt = bid & 127, nt = bid >> 7;
  const long m0 = (long)mt << 6;
  const int n0 = nt << 7;

  const int lane = t & 63, w = t >> 6;
  const int lc = lane & 31, hg = lane >> 5;

  v16i acc[2] = {};

  const int am = t >> 2, ah = t & 3;
  const char* Arow = A + (m0 + am) * (long)K + ah * 16;
  const int aoff = am * 80 + ah * 16;
  const int bm = t >> 1, bh = t & 1;
  const char* Brow = Btg + (long)(n0 + bm) * K + bh * 32;
  const int boff = bm * 80 + bh * 32;

  const int abo = lc * 80 + hg * 16;
  const int bbo = (w * 32 + lc) * 80 + hg * 16;

  int4 ar, br0, br1;
  auto LOAD = [&](int kb) {
    ar  = *(const int4*)(Arow + kb);
    br0 = *(const int4*)(Brow + kb);
    br1 = *(const int4*)(Brow + kb + 16);
  };
  auto STORE = [&](int stage) {
    char* base = smem + stage * 15360;
    *(int4*)(base + aoff) = ar;
    *(int4*)(base + 5120 + boff)      = br0;
    *(int4*)(base + 5120 + boff + 16) = br1;
  };

  const int kiters = K >> 6;
  LOAD(0);
  STORE(0);
  __syncthreads();

  for (int kt = 0; kt < kiters; ++kt) {
    if (kt + 1 < kiters) LOAD((kt + 1) << 6);
    const char* base = smem + (kt & 1) * 15360;
    const char* Ab = base + abo;
    const char* Bb = base + 5120 + bbo;
    #pragma unroll
    for (int ks = 0; ks < 2; ++ks) {
      v4i a0 = *(const v4i*)(Ab + ks * 32);
      v4i a1 = *(const v4i*)(Ab + 32 * 80 + ks * 32);
      v4i b  = *(const v4i*)(Bb + ks * 32);
      acc[0] = __builtin_amdgcn_mfma_i32_32x32x32_i8(a0, b, acc[0], 0, 0, 0);
      acc[1] = __builtin_amdgcn_mfma_i32_32x32x32_i8(a1, b, acc[1], 0, 0, 0);
    }
    if (kt + 1 < kiters) {
      STORE((kt + 1) & 1);
      __syncthreads();
    }
  }

  const int gcl = w * 32 + lc;
  const int bs = bsum[n0 + gcl];
  #pragma unroll
  for (int tm = 0; tm < 2; ++tm) {
    #pragma unroll
    for (int r = 0; r < 16; ++r) {
      const int row = tm * 32 + (hg << 2) + (r & 3) + ((r >> 2) << 3);
      Iout[(m0 + row) * 1024 + n0 + gcl] = (int)(signed char)(acc[tm][r] + bs);
    }
  }
}

// ---------------------------------------------------------------------------
// Layer 3: 16x128 tile, 512 blocks (2/CU), mfma_i32_16x16x64_i8, 2-stage.
// A = h2 int32 from d_out, packed to int8 in staging. (Verified R7/R8.)
// ---------------------------------------------------------------------------
__global__ __launch_bounds__(256, 2) void gemm3_kernel(
    const int* __restrict__ h2, const char* __restrict__ Btg,
    const int* __restrict__ bsum, int* __restrict__ Iout) {
  // stage: As 16x80 (1280) + Bs 128x80 (10240) = 11520; x2 = 23040
  __shared__ __align__(16) char smem[23040];
  const int t = threadIdx.x;
  const int m0 = blockIdx.x << 4;
  const int lane = t & 63, w = t >> 6;
  const int l16 = lane & 15, q = lane >> 4;
  v4i acc0 = {}, acc1 = {};

  const int am = t >> 4, ah = t & 15;      // 16 rows x 16 thr x 4 ints
  const int* Arow = h2 + (long)(m0 + am) * 1024 + ah * 4;
  const int aoff = am * 80 + ah * 4;
  const int bm = t >> 1, bh = t & 1;       // 128 rows x 2 thr x 32 B
  const char* Brow = Btg + (long)bm * 1024 + bh * 32;
  const int boff = bm * 80 + bh * 32;

  const int abo  = l16 * 80 + q * 16;
  const int bbo0 = (w * 32 + l16) * 80 + q * 16;
  const int bbo1 = (w * 32 + 16 + l16) * 80 + q * 16;

  int4 ar, br0, br1;
  auto LOAD = [&](int kt) {
    const int kb = kt << 6;
    ar  = *(const int4*)(Arow + kb);
    br0 = *(const int4*)(Brow + kb);
    br1 = *(const int4*)(Brow + kb + 16);
  };
  auto STORE = [&](int stage) {
    char* base = smem + stage * 11520;
    *(int*)(base + aoff) = pack4i(ar.x, ar.y, ar.z, ar.w);
    *(int4*)(base + 1280 + boff)      = br0;
    *(int4*)(base + 1280 + boff + 16) = br1;
  };
  auto MFMA = [&](int stage) {
    const char* base = smem + stage * 11520;
    v4i a  = *(const v4i*)(base + abo);
    v4i b0 = *(const v4i*)(base + 1280 + bbo0);
    v4i b1 = *(const v4i*)(base + 1280 + bbo1);
    acc0 = __builtin_amdgcn_mfma_i32_16x16x64_i8(a, b0, acc0, 0, 0, 0);
    acc1 = __builtin_amdgcn_mfma_i32_16x16x64_i8(a, b1, acc1, 0, 0, 0);
  };

  LOAD(0); STORE(0); __syncthreads();
  for (int kt = 0; kt < 16; ++kt) {
    if (kt + 1 < 16) LOAD(kt + 1);
    MFMA(kt & 1);
    if (kt + 1 < 16) { STORE((kt + 1) & 1); __syncthreads(); }
  }

  const int c0 = w * 32 + l16;       // cols {0-15,32-47,64-79,96-111}
  const int c1 = c0 + 16;            // cols {16-31,48-63,80-95,112-127}
  if (c0 < 100) {
    const int b = bsum[c0];
    #pragma unroll
    for (int r = 0; r < 4; ++r)
      Iout[(long)(m0 + q * 4 + r) * 100 + c0] = (int)(signed char)(acc0[r] + b);
  }
  if (c1 < 100) {
    const int b = bsum[c1];
    #pragma unroll
    for (int r = 0; r < 4; ++r)
      Iout[(long)(m0 + q * 4 + r) * 100 + c1] = (int)(signed char)(acc1[r] + b);
  }
}

// ---------------------------------------------------------------------------
// ws (12.7 MB): Bt1 | Bt2 | Bt3 | bs1 | bs2 | bs3 | A2
// No X8/H8 scratch anymore — gemm1 consumes X and H int32 directly (R3).
// ---------------------------------------------------------------------------
extern "C" void kernel_launch(void* const* d_in, const int* in_sizes, int n_in,
                              void* d_out, int out_size, void* d_ws, size_t ws_size,
                              hipStream_t stream) {
  (void)in_sizes; (void)n_in; (void)out_size; (void)ws_size;
  const int* W1  = (const int*)d_in[0];
  const int* b1  = (const int*)d_in[1];
  const int* W2  = (const int*)d_in[2];
  const int* b2  = (const int*)d_in[3];
  const int* W3  = (const int*)d_in[4];
  const int* b3  = (const int*)d_in[5];
  const int* E1  = (const int*)d_in[6];
  const int* eb1 = (const int*)d_in[7];
  const int* E2  = (const int*)d_in[8];
  const int* eb2 = (const int*)d_in[9];
  const int* E3  = (const int*)d_in[10];
  const int* eb3 = (const int*)d_in[11];
  const int* X   = (const int*)d_in[12];   // [8192][3072] int32
  const int* H   = (const int*)d_in[13];   // [8192][1024] int32
  int* out = (int*)d_out;                  // h2 [8192*1024] then out [8192*100]

  char* ws  = (char*)d_ws;
  char* Bt1 = ws;                          // 3,145,728
  char* Bt2 = Bt1 + 3145728;               // 1,048,576
  char* Bt3 = Bt2 + 1048576;               //   131,072 (rows 100..127 zeroed)
  int*  bs1 = (int*)(Bt3 + 131072);        // 1024 ints
  int*  bs2 = bs1 + 1024;                  // 1024 ints
  int*  bs3 = bs2 + 1024;                  //  128 ints
  char* A2  = (char*)(bs3 + 128);          // 8,388,608 int8

  pack_weights_kernel<<<dim3(265), dim3(256), 0, stream>>>(
      W1, E1, Bt1, W2, E2, Bt2, W3, E3, Bt3,
      b1, eb1, bs1, b2, eb2, bs2, b3, eb3, bs3);

  // Layer 1: X (int32, fused pack) -> i2c ; epilogue adds trunc8(H) -> A2
  gemm1_kernel<<<dim3(1024), dim3(256), 0, stream>>>(X, Bt1, bs1, H, A2);

  // Layer 2: h2 -> d_out (int32)
  gemm2_kernel<<<dim3(1024), dim3(256), 0, stream>>>(A2, Bt2, bs2, out);

  // Layer 3: reads h2 from d_out (int32), writes out region (int32)
  gemm3_kernel<<<dim3(512), dim3(256), 0, stream>>>(
      out, Bt3, bs3, out + 8388608);
}

// Round 4
// 310.558 us; speedup vs baseline: 1.0936x; 1.0936x over previous
//
#include <hip/hip_runtime.h>

typedef int v4i  __attribute__((ext_vector_type(4)));
typedef int v16i __attribute__((ext_vector_type(16)));

__device__ __forceinline__ int pack4i(int a, int b, int c, int d) {
  return (a & 255) | ((b & 255) << 8) | ((c & 255) << 16) | ((d & 255) << 24);
}
// SWAR per-byte add (mod-256 per lane-byte)
__device__ __forceinline__ int badd4(int a, int b) {
  return ((a & 0x7f7f7f7f) + (b & 0x7f7f7f7f)) ^ ((a ^ b) & 0x80808080);
}

// ---------------------------------------------------------------------------
// Pack (W + E) -> int8, transposed Bt[n][k] (row stride K bytes).
// Tile: 64 n x 256 k per block, 256 threads. Zero-pads n >= N rows.
// LDS: 256 k-rows x 68 B stride = 17408 B.
// ---------------------------------------------------------------------------
__device__ void pack_tile(const int* __restrict__ W, const int* __restrict__ E,
                          char* __restrict__ Bt, int K, int N,
                          int nx, int ky, char* lin) {
  const int t = threadIdx.x;
  const int n0 = nx * 64, k0 = ky * 256;
  {
    const int c  = t & 15;          // column group: 4 ints = 16 B
    const int kq = t >> 4;          // 0..15
    const int ng = n0 + c * 4;
    #pragma unroll 4
    for (int s = 0; s < 16; ++s) {
      const int k = s * 16 + kq;
      const long grow = (long)(k0 + k) * N;
      int a0, a1, a2, a3;
      if (ng + 3 < N) {
        int4 wv = *(const int4*)(W + grow + ng);
        int4 ev = *(const int4*)(E + grow + ng);
        a0 = wv.x + ev.x; a1 = wv.y + ev.y; a2 = wv.z + ev.z; a3 = wv.w + ev.w;
      } else {
        a0 = (ng + 0 < N) ? W[grow + ng + 0] + E[grow + ng + 0] : 0;
        a1 = (ng + 1 < N) ? W[grow + ng + 1] + E[grow + ng + 1] : 0;
        a2 = (ng + 2 < N) ? W[grow + ng + 2] + E[grow + ng + 2] : 0;
        a3 = (ng + 3 < N) ? W[grow + ng + 3] + E[grow + ng + 3] : 0;
      }
      *(int*)(lin + k * 68 + c * 4) = pack4i(a0, a1, a2, a3);
    }
  }
  __syncthreads();
  {
    const int n = t & 63, kq = t >> 6;
    char* dst = Bt + (long)(n0 + n) * K + k0 + (kq << 6);
    int outv[16];
    #pragma unroll
    for (int g = 0; g < 16; ++g) {
      const int k = (kq << 6) + (g << 2);
      outv[g] = pack4i(lin[(k + 0) * 68 + n], lin[(k + 1) * 68 + n],
                       lin[(k + 2) * 68 + n], lin[(k + 3) * 68 + n]);
    }
    #pragma unroll
    for (int g = 0; g < 4; ++g)
      *(int4*)(dst + (g << 4)) =
          make_int4(outv[g * 4], outv[g * 4 + 1], outv[g * 4 + 2], outv[g * 4 + 3]);
  }
}

// ---------------------------------------------------------------------------
// Weights + biases. 265 blocks. (R2: small, never in top-5.)
// ---------------------------------------------------------------------------
__global__ __launch_bounds__(256) void pack_weights_kernel(
    const int* W1, const int* E1, char* Bt1,
    const int* W2, const int* E2, char* Bt2,
    const int* W3, const int* E3, char* Bt3,
    const int* b1, const int* eb1, int* bs1,
    const int* b2, const int* eb2, int* bs2,
    const int* b3, const int* eb3, int* bs3) {
  __shared__ __align__(16) char smem[17408];
  const int bid = blockIdx.x;
  if (bid < 192) {
    pack_tile(W1, E1, Bt1, 3072, 1024, bid % 16, bid / 16, smem);
  } else if (bid < 256) {
    const int l = bid - 192;
    pack_tile(W2, E2, Bt2, 1024, 1024, l % 16, l / 16, smem);
  } else if (bid < 264) {
    const int l = bid - 256;
    pack_tile(W3, E3, Bt3, 1024, 100, l & 1, l >> 1, smem);
  } else {
    const int t = threadIdx.x;
    for (int i = t; i < 1024; i += 256) {
      bs1[i] = b1[i] + eb1[i];
      bs2[i] = b2[i] + eb2[i];
    }
    for (int i = t; i < 128; i += 256)
      bs3[i] = (i < 100) ? (b3[i] + eb3[i]) : 0;
  }
}

// ---------------------------------------------------------------------------
// R4: both big GEMMs move to a 128x256 tile, BK=64, 512 thr (8 waves, 2x4),
// 2-stage LDS dbuf + DEPTH-2 register prefetch with two NAMED register sets
// (static indexing, no scratch). R3 counters showed the 2-phase 64x128 loop
// is latency-bound: MfmaUtil 7.5%, VALUBusy 10.8%, HBM 15% — 4 MFMAs (~36cy)
// per ~500cy load-wait. Now: 8 MFMAs/wave/step and loads issued 2 steps
// ahead, so the compiler's dependence-driven s_waitcnt is a COUNTED wait
// (the store of set Y only drains Y's 6 loads; set X stays in flight).
// BN=256 also halves X's L3-side re-read (4 n-tiles, not 8).
// Wave w -> (wm,wn) = (w>>2, w&3): 64x64 quadrant = 2x2 MFMA tiles.
// Stage: As [128][80] (10240) + Bs [256][80] (20480) = 30720; x2 = 61440.
// Grid 64x4 = 256 (1 block/CU); bid&63 = mt, 64%8==0 -> the 4 blocks
// sharing an A-panel sit on one XCD's L2.
// ---------------------------------------------------------------------------
#define MFMA_I8(a, b, c) __builtin_amdgcn_mfma_i32_32x32x32_i8(a, b, c, 0, 0, 0)

__global__ __launch_bounds__(512, 2) void gemm1_kernel(
    const int* __restrict__ X, const char* __restrict__ Btg,
    const int* __restrict__ bsum, const int* __restrict__ H,
    char* __restrict__ A8out) {
  const int K = 3072;
  __shared__ __align__(16) char smem[61440];
  const int t = threadIdx.x;
  const int bid = blockIdx.x;
  const int mt = bid & 63, nt = bid >> 6;
  const long m0 = (long)mt << 7;
  const int n0 = nt << 8;

  const int lane = t & 63, w = t >> 6;
  const int lc = lane & 31, hg = lane >> 5;
  const int wm = w >> 2, wn = w & 3;

  v16i acc[2][2] = {};

  // A staging: 128 rows x 4 thr x 16 ints (64 B int32 -> 16 B packed)
  const int arow = t >> 2, aq = t & 3;
  const int* Xrow = X + (m0 + arow) * (long)K + aq * 16;
  const int aoff = arow * 80 + aq * 16;
  // B staging: 256 rows x 2 thr x 32 B (already int8)
  const int brow = t >> 1, bh = t & 1;
  const char* Brow = Btg + (long)(n0 + brow) * K + bh * 32;
  const int boff = 10240 + brow * 80 + bh * 32;

  const int aro = (wm * 64 + lc) * 80 + hg * 16;
  const int bro = 10240 + (wn * 64 + lc) * 80 + hg * 16;

  int4 xa0, xa1, xa2, xa3, xb0, xb1;   // prefetch set X
  int4 ya0, ya1, ya2, ya3, yb0, yb1;   // prefetch set Y

#define G1_LOAD(p0,p1,p2,p3,p4,p5,kt) do {                        \
    const int kb_ = (kt) << 6;                                    \
    const int* p_ = Xrow + kb_;                                   \
    p0 = *(const int4*)(p_);      p1 = *(const int4*)(p_ + 4);    \
    p2 = *(const int4*)(p_ + 8);  p3 = *(const int4*)(p_ + 12);   \
    p4 = *(const int4*)(Brow + kb_);                              \
    p5 = *(const int4*)(Brow + kb_ + 16);                         \
  } while (0)
#define G1_STORE(p0,p1,p2,p3,p4,p5,stage) do {                    \
    char* base_ = smem + (stage) * 30720;                         \
    *(int4*)(base_ + aoff) = make_int4(                           \
        pack4i(p0.x,p0.y,p0.z,p0.w), pack4i(p1.x,p1.y,p1.z,p1.w), \
        pack4i(p2.x,p2.y,p2.z,p2.w), pack4i(p3.x,p3.y,p3.z,p3.w));\
    *(int4*)(base_ + boff)      = p4;                             \
    *(int4*)(base_ + boff + 16) = p5;                             \
  } while (0)

  auto MFMA_STEP = [&](int stage) {
    const char* base = smem + stage * 30720;
    #pragma unroll
    for (int ks = 0; ks < 2; ++ks) {
      v4i a0 = *(const v4i*)(base + aro + ks * 32);
      v4i a1 = *(const v4i*)(base + aro + 32 * 80 + ks * 32);
      v4i b0 = *(const v4i*)(base + bro + ks * 32);
      v4i b1 = *(const v4i*)(base + bro + 32 * 80 + ks * 32);
      acc[0][0] = MFMA_I8(a0, b0, acc[0][0]);
      acc[0][1] = MFMA_I8(a0, b1, acc[0][1]);
      acc[1][0] = MFMA_I8(a1, b0, acc[1][0]);
      acc[1][1] = MFMA_I8(a1, b1, acc[1][1]);
    }
  };

  const int KIT = K >> 6;              // 48 (even)
  G1_LOAD(xa0, xa1, xa2, xa3, xb0, xb1, 0);
  G1_LOAD(ya0, ya1, ya2, ya3, yb0, yb1, 1);
  G1_STORE(xa0, xa1, xa2, xa3, xb0, xb1, 0);
  __syncthreads();

  for (int kt = 0; kt < KIT; kt += 2) {
    if (kt + 2 < KIT) G1_LOAD(xa0, xa1, xa2, xa3, xb0, xb1, kt + 2);
    MFMA_STEP(0);
    G1_STORE(ya0, ya1, ya2, ya3, yb0, yb1, 1);
    __syncthreads();
    if (kt + 3 < KIT) G1_LOAD(ya0, ya1, ya2, ya3, yb0, yb1, kt + 3);
    MFMA_STEP(1);
    if (kt + 2 < KIT) {
      G1_STORE(xa0, xa1, xa2, xa3, xb0, xb1, 0);
      __syncthreads();
    }
  }

  // Epilogue. C/D: col = lc, row = (r&3) + 8*(r>>2) + 4*hg per 32x32 tile.
  __syncthreads();                     // stage buffers now dead
  const int bsj0 = bsum[n0 + wn * 64 + lc];
  const int bsj1 = bsum[n0 + wn * 64 + 32 + lc];
  #pragma unroll
  for (int i = 0; i < 2; ++i) {
    #pragma unroll
    for (int j = 0; j < 2; ++j) {
      const int bsv = j ? bsj1 : bsj0;
      const int col = wn * 64 + j * 32 + lc;
      #pragma unroll
      for (int r = 0; r < 16; ++r) {
        const int row = wm * 64 + i * 32 + (hg << 2) + (r & 3) + ((r >> 2) << 3);
        smem[row * 272 + col] = (char)(acc[i][j][r] + bsv);
      }
    }
  }
  __syncthreads();
  // readout: thread -> row t>>2, 64 B at (t&3)*64 ; SWAR-add trunc8(H int32)
  const int erow = t >> 2, seg = t & 3;
  const char* src = smem + erow * 272 + seg * 64;
  const long gm = m0 + erow;
  const long gco = gm * 1024 + n0 + seg * 64;
  const int* hp = H + gco;
  #pragma unroll
  for (int g = 0; g < 4; ++g) {
    int4 s  = *(const int4*)(src + g * 16);
    int4 h0 = *(const int4*)(hp + g * 16);
    int4 h1 = *(const int4*)(hp + g * 16 + 4);
    int4 h2 = *(const int4*)(hp + g * 16 + 8);
    int4 h3 = *(const int4*)(hp + g * 16 + 12);
    s = make_int4(badd4(s.x, pack4i(h0.x, h0.y, h0.z, h0.w)),
                  badd4(s.y, pack4i(h1.x, h1.y, h1.z, h1.w)),
                  badd4(s.z, pack4i(h2.x, h2.y, h2.z, h2.w)),
                  badd4(s.w, pack4i(h3.x, h3.y, h3.z, h3.w)));
    *(int4*)(A8out + gco + g * 16) = s;
  }
}

// ---------------------------------------------------------------------------
// Layer 2: same 128x256 / depth-2 template, A already int8, K=1024.
// Epilogue: Iout = trunc8(acc+bs) as int32, direct.
// ---------------------------------------------------------------------------
__global__ __launch_bounds__(512, 2) void gemm2_kernel(
    const char* __restrict__ A, const char* __restrict__ Btg,
    const int* __restrict__ bsum, int* __restrict__ Iout) {
  const int K = 1024;
  __shared__ __align__(16) char smem[61440];
  const int t = threadIdx.x;
  const int bid = blockIdx.x;
  const int mt = bid & 63, nt = bid >> 6;
  const long m0 = (long)mt << 7;
  const int n0 = nt << 8;

  const int lane = t & 63, w = t >> 6;
  const int lc = lane & 31, hg = lane >> 5;
  const int wm = w >> 2, wn = w & 3;

  v16i acc[2][2] = {};

  // A staging: 128 rows x 4 thr x 16 B (int8)
  const int arow = t >> 2, aq = t & 3;
  const char* Arow = A + (m0 + arow) * (long)K + aq * 16;
  const int aoff = arow * 80 + aq * 16;
  // B staging: 256 rows x 2 thr x 32 B
  const int brow = t >> 1, bh = t & 1;
  const char* Brow = Btg + (long)(n0 + brow) * K + bh * 32;
  const int boff = 10240 + brow * 80 + bh * 32;

  const int aro = (wm * 64 + lc) * 80 + hg * 16;
  const int bro = 10240 + (wn * 64 + lc) * 80 + hg * 16;

  int4 xa0, xb0, xb1;                  // prefetch set X
  int4 ya0, yb0, yb1;                  // prefetch set Y

#define G2_LOAD(p0,p4,p5,kt) do {                                 \
    const int kb_ = (kt) << 6;                                    \
    p0 = *(const int4*)(Arow + kb_);                              \
    p4 = *(const int4*)(Brow + kb_);                              \
    p5 = *(const int4*)(Brow + kb_ + 16);                         \
  } while (0)
#define G2_STORE(p0,p4,p5,stage) do {                             \
    char* base_ = smem + (stage) * 30720;                         \
    *(int4*)(base_ + aoff)      = p0;                             \
    *(int4*)(base_ + boff)      = p4;                             \
    *(int4*)(base_ + boff + 16) = p5;                             \
  } while (0)

  auto MFMA_STEP = [&](int stage) {
    const char* base = smem + stage * 30720;
    #pragma unroll
    for (int ks = 0; ks < 2; ++ks) {
      v4i a0 = *(const v4i*)(base + aro + ks * 32);
      v4i a1 = *(const v4i*)(base + aro + 32 * 80 + ks * 32);
      v4i b0 = *(const v4i*)(base + bro + ks * 32);
      v4i b1 = *(const v4i*)(base + bro + 32 * 80 + ks * 32);
      acc[0][0] = MFMA_I8(a0, b0, acc[0][0]);
      acc[0][1] = MFMA_I8(a0, b1, acc[0][1]);
      acc[1][0] = MFMA_I8(a1, b0, acc[1][0]);
      acc[1][1] = MFMA_I8(a1, b1, acc[1][1]);
    }
  };

  const int KIT = K >> 6;              // 16 (even)
  G2_LOAD(xa0, xb0, xb1, 0);
  G2_LOAD(ya0, yb0, yb1, 1);
  G2_STORE(xa0, xb0, xb1, 0);
  __syncthreads();

  for (int kt = 0; kt < KIT; kt += 2) {
    if (kt + 2 < KIT) G2_LOAD(xa0, xb0, xb1, kt + 2);
    MFMA_STEP(0);
    G2_STORE(ya0, yb0, yb1, 1);
    __syncthreads();
    if (kt + 3 < KIT) G2_LOAD(ya0, yb0, yb1, kt + 3);
    MFMA_STEP(1);
    if (kt + 2 < KIT) {
      G2_STORE(xa0, xb0, xb1, 0);
      __syncthreads();
    }
  }

  const int bsj0 = bsum[n0 + wn * 64 + lc];
  const int bsj1 = bsum[n0 + wn * 64 + 32 + lc];
  #pragma unroll
  for (int i = 0; i < 2; ++i) {
    #pragma unroll
    for (int j = 0; j < 2; ++j) {
      const int bsv = j ? bsj1 : bsj0;
      const int col = n0 + wn * 64 + j * 32 + lc;
      #pragma unroll
      for (int r = 0; r < 16; ++r) {
        const long row = m0 + wm * 64 + i * 32 + (hg << 2) + (r & 3) + ((r >> 2) << 3);
        Iout[row * 1024 + col] = (int)(signed char)(acc[i][j][r] + bsv);
      }
    }
  }
}

// ---------------------------------------------------------------------------
// Layer 3: 16x128 tile, 512 blocks (2/CU), mfma_i32_16x16x64_i8, 2-stage.
// A = h2 int32 from d_out, packed to int8 in staging. (Verified R7/R8.)
// ---------------------------------------------------------------------------
__global__ __launch_bounds__(256, 2) void gemm3_kernel(
    const int* __restrict__ h2, const char* __restrict__ Btg,
    const int* __restrict__ bsum, int* __restrict__ Iout) {
  // stage: As 16x80 (1280) + Bs 128x80 (10240) = 11520; x2 = 23040
  __shared__ __align__(16) char smem[23040];
  const int t = threadIdx.x;
  const int m0 = blockIdx.x << 4;
  const int lane = t & 63, w = t >> 6;
  const int l16 = lane & 15, q = lane >> 4;
  v4i acc0 = {}, acc1 = {};

  const int am = t >> 4, ah = t & 15;      // 16 rows x 16 thr x 4 ints
  const int* Arow = h2 + (long)(m0 + am) * 1024 + ah * 4;
  const int aoff = am * 80 + ah * 4;
  const int bm = t >> 1, bh = t & 1;       // 128 rows x 2 thr x 32 B
  const char* Brow = Btg + (long)bm * 1024 + bh * 32;
  const int boff = bm * 80 + bh * 32;

  const int abo  = l16 * 80 + q * 16;
  const int bbo0 = (w * 32 + l16) * 80 + q * 16;
  const int bbo1 = (w * 32 + 16 + l16) * 80 + q * 16;

  int4 ar, br0, br1;
  auto LOAD = [&](int kt) {
    const int kb = kt << 6;
    ar  = *(const int4*)(Arow + kb);
    br0 = *(const int4*)(Brow + kb);
    br1 = *(const int4*)(Brow + kb + 16);
  };
  auto STORE = [&](int stage) {
    char* base = smem + stage * 11520;
    *(int*)(base + aoff) = pack4i(ar.x, ar.y, ar.z, ar.w);
    *(int4*)(base + 1280 + boff)      = br0;
    *(int4*)(base + 1280 + boff + 16) = br1;
  };
  auto MFMA = [&](int stage) {
    const char* base = smem + stage * 11520;
    v4i a  = *(const v4i*)(base + abo);
    v4i b0 = *(const v4i*)(base + 1280 + bbo0);
    v4i b1 = *(const v4i*)(base + 1280 + bbo1);
    acc0 = __builtin_amdgcn_mfma_i32_16x16x64_i8(a, b0, acc0, 0, 0, 0);
    acc1 = __builtin_amdgcn_mfma_i32_16x16x64_i8(a, b1, acc1, 0, 0, 0);
  };

  LOAD(0); STORE(0); __syncthreads();
  for (int kt = 0; kt < 16; ++kt) {
    if (kt + 1 < 16) LOAD(kt + 1);
    MFMA(kt & 1);
    if (kt + 1 < 16) { STORE((kt + 1) & 1); __syncthreads(); }
  }

  const int c0 = w * 32 + l16;       // cols {0-15,32-47,64-79,96-111}
  const int c1 = c0 + 16;            // cols {16-31,48-63,80-95,112-127}
  if (c0 < 100) {
    const int b = bsum[c0];
    #pragma unroll
    for (int r = 0; r < 4; ++r)
      Iout[(long)(m0 + q * 4 + r) * 100 + c0] = (int)(signed char)(acc0[r] + b);
  }
  if (c1 < 100) {
    const int b = bsum[c1];
    #pragma unroll
    for (int r = 0; r < 4; ++r)
      Iout[(long)(m0 + q * 4 + r) * 100 + c1] = (int)(signed char)(acc1[r] + b);
  }
}

// ---------------------------------------------------------------------------
// ws (12.7 MB): Bt1 | Bt2 | Bt3 | bs1 | bs2 | bs3 | A2
// ---------------------------------------------------------------------------
extern "C" void kernel_launch(void* const* d_in, const int* in_sizes, int n_in,
                              void* d_out, int out_size, void* d_ws, size_t ws_size,
                              hipStream_t stream) {
  (void)in_sizes; (void)n_in; (void)out_size; (void)ws_size;
  const int* W1  = (const int*)d_in[0];
  const int* b1  = (const int*)d_in[1];
  const int* W2  = (const int*)d_in[2];
  const int* b2  = (const int*)d_in[3];
  const int* W3  = (const int*)d_in[4];
  const int* b3  = (const int*)d_in[5];
  const int* E1  = (const int*)d_in[6];
  const int* eb1 = (const int*)d_in[7];
  const int* E2  = (const int*)d_in[8];
  const int* eb2 = (const int*)d_in[9];
  const int* E3  = (const int*)d_in[10];
  const int* eb3 = (const int*)d_in[11];
  const int* X   = (const int*)d_in[12];   // [8192][3072] int32
  const int* H   = (const int*)d_in[13];   // [8192][1024] int32
  int* out = (int*)d_out;                  // h2 [8192*1024] then out [8192*100]

  char* ws  = (char*)d_ws;
  char* Bt1 = ws;                          // 3,145,728
  char* Bt2 = Bt1 + 3145728;               // 1,048,576
  char* Bt3 = Bt2 + 1048576;               //   131,072 (rows 100..127 zeroed)
  int*  bs1 = (int*)(Bt3 + 131072);        // 1024 ints
  int*  bs2 = bs1 + 1024;                  // 1024 ints
  int*  bs3 = bs2 + 1024;                  //  128 ints
  char* A2  = (char*)(bs3 + 128);          // 8,388,608 int8

  pack_weights_kernel<<<dim3(265), dim3(256), 0, stream>>>(
      W1, E1, Bt1, W2, E2, Bt2, W3, E3, Bt3,
      b1, eb1, bs1, b2, eb2, bs2, b3, eb3, bs3);

  // Layer 1: X (int32, fused pack) -> i2c ; epilogue adds trunc8(H) -> A2
  gemm1_kernel<<<dim3(256), dim3(512), 0, stream>>>(X, Bt1, bs1, H, A2);

  // Layer 2: h2 -> d_out (int32)
  gemm2_kernel<<<dim3(256), dim3(512), 0, stream>>>(A2, Bt2, bs2, out);

  // Layer 3: reads h2 from d_out (int32), writes out region (int32)
  gemm3_kernel<<<dim3(512), dim3(256), 0, stream>>>(
      out, Bt3, bs3, out + 8388608);
}